// Round 1
// baseline (184.119 us; speedup 1.0000x reference)
//
#include <hip/hip_runtime.h>
#include <stdint.h>

typedef __attribute__((ext_vector_type(8))) short short8;
typedef __attribute__((ext_vector_type(4))) float f32x4;

#define MFMA16(a, b, c) __builtin_amdgcn_mfma_f32_16x16x32_bf16((a), (b), (c), 0, 0, 0)

typedef __attribute__((address_space(1))) const void GVoid;
typedef __attribute__((address_space(3))) void LVoid;
#define GLDS16(g, l) __builtin_amdgcn_global_load_lds((GVoid*)(g), (LVoid*)(l), 16, 0, 0)

#define L2E 1.4426950408889634f

__device__ __forceinline__ unsigned short f2bf(float f) {
  unsigned int u = __builtin_bit_cast(unsigned int, f);
  u += 0x7fffu + ((u >> 16) & 1u);   // RNE (finite values only)
  return (unsigned short)(u >> 16);
}

// ---------------------------------------------------------------------------
// Kernel 1: Q/K/V projections. Q pre-scaled by 1/sqrt(128). V stored transposed.
//   Qg,Kg: bf16 [B*S][128] row-major.  Vtg: bf16 [B][128][S].
// ---------------------------------------------------------------------------
__global__ __launch_bounds__(256) void k_proj(
    const float* __restrict__ x,
    const float* __restrict__ Wq, const float* __restrict__ bq,
    const float* __restrict__ Wk, const float* __restrict__ bk,
    const float* __restrict__ Wv, const float* __restrict__ bv,
    unsigned short* __restrict__ Qg, unsigned short* __restrict__ Kg,
    unsigned short* __restrict__ Vtg)
{
  __shared__ __align__(16) unsigned short wt[128 * 128];  // swizzled W^T, 32KB
  const int tid  = threadIdx.x;
  const int lane = tid & 63;
  const int wid  = tid >> 6;
  const int l15  = lane & 15;
  const int g    = lane >> 4;
  const int r0   = blockIdx.x * 64 + wid * 16;

  // A fragments: 16 rows of x, bf16. lane holds row l15, k = g*8 + kt*32 (+j)
  short8 af[4];
  {
    const float* xp = x + (r0 + l15) * 128 + g * 8;
#pragma unroll
    for (int kt = 0; kt < 4; ++kt) {
      float4 v0 = *(const float4*)(xp + kt * 32);
      float4 v1 = *(const float4*)(xp + kt * 32 + 4);
      short8 a;
      a[0] = (short)f2bf(v0.x); a[1] = (short)f2bf(v0.y);
      a[2] = (short)f2bf(v0.z); a[3] = (short)f2bf(v0.w);
      a[4] = (short)f2bf(v1.x); a[5] = (short)f2bf(v1.y);
      a[6] = (short)f2bf(v1.z); a[7] = (short)f2bf(v1.w);
      af[kt] = a;
    }
  }

  const float* Ws[3] = {Wq, Wk, Wv};
  const float* bs[3] = {bq, bk, bv};

  for (int wI = 0; wI < 3; ++wI) {
    __syncthreads();  // protect wt against previous iteration's readers
    const float* W = Ws[wI];
    // stage W^T bf16, XOR-swizzled: wt[n][ (c^(n&7))*8 + k&7 ] = W[k][n]
    for (int i = 0; i < 64; ++i) {
      int idx = i * 256 + tid;
      int k = idx >> 7, n = idx & 127;
      int cs = (k >> 3) ^ (n & 7);
      wt[n * 128 + cs * 8 + (k & 7)] = f2bf(W[idx]);
    }
    __syncthreads();

    float bias[8];
#pragma unroll
    for (int nt = 0; nt < 8; ++nt) bias[nt] = bs[wI][nt * 16 + l15];

    f32x4 acc[8];
#pragma unroll
    for (int nt = 0; nt < 8; ++nt) acc[nt] = (f32x4){0.f, 0.f, 0.f, 0.f};

#pragma unroll
    for (int nt = 0; nt < 8; ++nt) {
      const int n = nt * 16 + l15;
#pragma unroll
      for (int ks = 0; ks < 4; ++ks) {
        int cs = (ks * 4 + g) ^ (n & 7);
        short8 bf = *(const short8*)&wt[n * 128 + cs * 8];
        acc[nt] = MFMA16(af[ks], bf, acc[nt]);
      }
    }

    // D layout: col = l15 + nt*16, row = g*4 + r
    if (wI < 2) {
      unsigned short* Og = (wI == 0) ? Qg : Kg;
      const float sc = (wI == 0) ? 0.08838834764831845f : 1.0f;  // 1/sqrt(128)
#pragma unroll
      for (int nt = 0; nt < 8; ++nt) {
        int col = nt * 16 + l15;
#pragma unroll
        for (int r = 0; r < 4; ++r) {
          int m = r0 + g * 4 + r;
          Og[m * 128 + col] = f2bf((acc[nt][r] + bias[nt]) * sc);
        }
      }
    } else {
      // Vt: 4 consecutive s per lane -> one 8B store
#pragma unroll
      for (int nt = 0; nt < 8; ++nt) {
        int col = nt * 16 + l15;
        int m0 = r0 + g * 4;
        int bb = m0 >> 12, s0 = m0 & 4095;
        ushort4 pk;
        pk.x = f2bf(acc[nt][0] + bias[nt]);
        pk.y = f2bf(acc[nt][1] + bias[nt]);
        pk.z = f2bf(acc[nt][2] + bias[nt]);
        pk.w = f2bf(acc[nt][3] + bias[nt]);
        *(ushort4*)&Vtg[(bb * 128 + col) * 4096 + s0] = pk;
      }
    }
  }
}

// ---------------------------------------------------------------------------
// Kernel 2: flash attention. Block = (b, 64 q-rows), 4 waves:
//   wave = (qsub = wid&1 -> 32 q-rows, half = wid>>1 -> KV range of 2048).
// KVBLK=64 double-buffered via global_load_lds; in-LDS split-KV merge.
// LDS: K [2dbuf][2half][64][128] 64KB | Vt [2][2][128][64] 64KB | P [4][32][64] 16KB
// ---------------------------------------------------------------------------
#define KOFF 0
#define VOFF 65536
#define POFF 131072

__global__ __launch_bounds__(256) void k_attn(
    const unsigned short* __restrict__ Qg,
    const unsigned short* __restrict__ Kg,
    const unsigned short* __restrict__ Vtg,
    unsigned short* __restrict__ Ag)
{
  __shared__ __align__(16) char smem[147456];
  const int tid = threadIdx.x, lane = tid & 63, wid = tid >> 6;
  const int l15 = lane & 15, g = lane >> 4;
  // XCD-aware mapping: batch b lives on XCDs {2b, 2b+1} (K/V fit in 2x4MB L2)
  const int p = blockIdx.x;
  const int b = (p & 7) >> 1;
  const int qt = ((p >> 3) << 1) | (p & 1);
  const int qsub = wid & 1, half = wid >> 1;
  const int q0 = qt * 64 + qsub * 32;

  // Q fragments (pre-scaled): 2 subtiles x 4 k-slices
  short8 qf[2][4];
#pragma unroll
  for (int st = 0; st < 2; ++st) {
    const unsigned short* qp = Qg + (b * 4096 + q0 + st * 16 + l15) * 128 + g * 8;
#pragma unroll
    for (int kt = 0; kt < 4; ++kt) qf[st][kt] = *(const short8*)(qp + kt * 32);
  }

  f32x4 O[2][8];
#pragma unroll
  for (int st = 0; st < 2; ++st)
#pragma unroll
    for (int nt = 0; nt < 8; ++nt) O[st][nt] = (f32x4){0.f, 0.f, 0.f, 0.f};
  float mS[2][4], lS[2][4];
#pragma unroll
  for (int st = 0; st < 2; ++st)
#pragma unroll
    for (int r = 0; r < 4; ++r) { mS[st][r] = -3.0e38f; lS[st][r] = 0.f; }

  // stage K + Vt tiles for iteration t into dbuf d (wave wid stages one tile)
  auto stageAll = [&](int t, int d) {
    if (wid < 2) {
      const int h = wid;
      const int kv0 = h * 2048 + t * 64;
#pragma unroll
      for (int i = 0; i < 16; ++i) {
        int slot = i * 64 + lane;
        int r = slot >> 4, c = slot & 15;           // K tile row 0..63, 16B col 0..15
        const unsigned short* src = Kg + (b * 4096 + kv0 + r) * 128 + ((c ^ (r & 7)) * 8);
        char* dstu = smem + KOFF + ((d * 2 + h) * 1024 + i * 64) * 16;
        GLDS16(src, dstu);
      }
    } else {
      const int h = wid - 2;
      const int kv0 = h * 2048 + t * 64;
#pragma unroll
      for (int i = 0; i < 16; ++i) {
        int slot = i * 64 + lane;
        int r = slot >> 3, c = slot & 7;            // Vt tile row (d) 0..127, 16B col 0..7
        const unsigned short* src = Vtg + (b * 128 + r) * 4096 + kv0 + ((c ^ (r & 7)) * 8);
        char* dstu = smem + VOFF + ((d * 2 + h) * 1024 + i * 64) * 16;
        GLDS16(src, dstu);
      }
    }
  };

  stageAll(0, 0);
  __syncthreads();

  int cur = 0;
  for (int t = 0; t < 32; ++t) {
    if (t + 1 < 32) stageAll(t + 1, cur ^ 1);   // prefetch next tile (async)

    // ---- QK^T: S[32 q][64 kv] ----
    f32x4 sA[2][4];
#pragma unroll
    for (int st = 0; st < 2; ++st)
#pragma unroll
      for (int ct = 0; ct < 4; ++ct) sA[st][ct] = (f32x4){0.f, 0.f, 0.f, 0.f};

#pragma unroll
    for (int ct = 0; ct < 4; ++ct) {
#pragma unroll
      for (int ks = 0; ks < 4; ++ks) {
        int row = ct * 16 + l15;                 // kv row of K = B-frag col
        int cs = (ks * 4 + g) ^ (row & 7);
        short8 kf = *(const short8*)(smem + KOFF + ((cur * 2 + half) * 1024 + row * 16 + cs) * 16);
        sA[0][ct] = MFMA16(qf[0][ks], kf, sA[0][ct]);
        sA[1][ct] = MFMA16(qf[1][ks], kf, sA[1][ct]);
      }
    }

    // ---- online softmax (rows 4g+r, row-reduce over 16 lanes) + P -> LDS ----
#pragma unroll
    for (int st = 0; st < 2; ++st) {
      float mx[4];
#pragma unroll
      for (int r = 0; r < 4; ++r) {
        float v = fmaxf(fmaxf(sA[st][0][r], sA[st][1][r]), fmaxf(sA[st][2][r], sA[st][3][r]));
        v = fmaxf(v, __shfl_xor(v, 1, 64));
        v = fmaxf(v, __shfl_xor(v, 2, 64));
        v = fmaxf(v, __shfl_xor(v, 4, 64));
        v = fmaxf(v, __shfl_xor(v, 8, 64));
        mx[r] = v;
      }
      float fsc[4], ts[4];
#pragma unroll
      for (int r = 0; r < 4; ++r) {
        float mnew = fmaxf(mS[st][r], mx[r]);
        fsc[r] = exp2f((mS[st][r] - mnew) * L2E);
        mS[st][r] = mnew;
        ts[r] = 0.f;
      }
#pragma unroll
      for (int ct = 0; ct < 4; ++ct) {
        int kv = ct * 16 + l15;
#pragma unroll
        for (int r = 0; r < 4; ++r) {
          float pv = exp2f((sA[st][ct][r] - mS[st][r]) * L2E);
          ts[r] += pv;
          int row = st * 16 + g * 4 + r;
          int cs = (kv >> 3) ^ (row & 7);
          *(unsigned short*)(smem + POFF + (wid * 32 + row) * 128 + cs * 16 + (kv & 7) * 2) = f2bf(pv);
        }
      }
#pragma unroll
      for (int r = 0; r < 4; ++r) {
        float s = ts[r];
        s += __shfl_xor(s, 1, 64);
        s += __shfl_xor(s, 2, 64);
        s += __shfl_xor(s, 4, 64);
        s += __shfl_xor(s, 8, 64);
        lS[st][r] = lS[st][r] * fsc[r] + s;
      }
#pragma unroll
      for (int nt = 0; nt < 8; ++nt) {
        O[st][nt][0] *= fsc[0]; O[st][nt][1] *= fsc[1];
        O[st][nt][2] *= fsc[2]; O[st][nt][3] *= fsc[3];
      }
    }

    // ---- PV: O += P[32 q][64 kv] * V[64 kv][128 d] ----
    short8 pa[2][2];
#pragma unroll
    for (int st = 0; st < 2; ++st)
#pragma unroll
      for (int k2 = 0; k2 < 2; ++k2) {
        int row = st * 16 + l15;
        int cs = (k2 * 4 + g) ^ (row & 7);
        pa[st][k2] = *(const short8*)(smem + POFF + (wid * 32 + row) * 128 + cs * 16);
      }
#pragma unroll
    for (int nt = 0; nt < 8; ++nt) {
#pragma unroll
      for (int k2 = 0; k2 < 2; ++k2) {
        int drow = nt * 16 + l15;                // output col d = B-frag col
        int cs = (k2 * 4 + g) ^ (drow & 7);
        short8 vf = *(const short8*)(smem + VOFF + ((cur * 2 + half) * 1024 + drow * 8 + cs) * 16);
        O[0][nt] = MFMA16(pa[0][k2], vf, O[0][nt]);
        O[1][nt] = MFMA16(pa[1][k2], vf, O[1][nt]);
      }
    }

    __syncthreads();   // drains staging loads (vmcnt 0) + protects dbuf swap
    cur ^= 1;
  }

  // ---- split-KV merge (reuse K-tile LDS region) ----
  float* mo  = (float*)smem;             // [2 qsub][32][128] fp32 = 32KB
  float* mlp = (float*)(smem + 32768);   // [2 qsub * 32][2] (m, l)
  if (half == 1) {
#pragma unroll
    for (int st = 0; st < 2; ++st) {
#pragma unroll
      for (int nt = 0; nt < 8; ++nt) {
        int col = nt * 16 + l15;
#pragma unroll
        for (int r = 0; r < 4; ++r) {
          int q32 = st * 16 + g * 4 + r;
          mo[(qsub * 32 + q32) * 128 + col] = O[st][nt][r];
        }
      }
      if (l15 == 0) {
#pragma unroll
        for (int r = 0; r < 4; ++r) {
          int q32 = st * 16 + g * 4 + r;
          mlp[(qsub * 32 + q32) * 2 + 0] = mS[st][r];
          mlp[(qsub * 32 + q32) * 2 + 1] = lS[st][r];
        }
      }
    }
  }
  __syncthreads();
  if (half == 0) {
#pragma unroll
    for (int st = 0; st < 2; ++st) {
      float c1[4], c2[4];
#pragma unroll
      for (int r = 0; r < 4; ++r) {
        int q32 = st * 16 + g * 4 + r;
        float m2 = mlp[(qsub * 32 + q32) * 2 + 0];
        float l2 = mlp[(qsub * 32 + q32) * 2 + 1];
        float m1 = mS[st][r], l1 = lS[st][r];
        float mm = fmaxf(m1, m2);
        float a1 = exp2f((m1 - mm) * L2E);
        float a2 = exp2f((m2 - mm) * L2E);
        float den = l1 * a1 + l2 * a2;
        c1[r] = a1 / den;
        c2[r] = a2 / den;
      }
#pragma unroll
      for (int nt = 0; nt < 8; ++nt) {
        int col = nt * 16 + l15;
#pragma unroll
        for (int r = 0; r < 4; ++r) {
          int q32 = st * 16 + g * 4 + r;
          float o = O[st][nt][r] * c1[r] + mo[(qsub * 32 + q32) * 128 + col] * c2[r];
          Ag[(b * 4096 + q0 + q32) * 128 + col] = f2bf(o);
        }
      }
    }
  }
}

// ---------------------------------------------------------------------------
// Kernel 3: out = attended @ Wo + bo  (fp32 output)
// ---------------------------------------------------------------------------
__global__ __launch_bounds__(256) void k_out(
    const unsigned short* __restrict__ Ag,
    const float* __restrict__ Wo, const float* __restrict__ bo,
    float* __restrict__ out)
{
  __shared__ __align__(16) unsigned short wt[128 * 128];
  const int tid = threadIdx.x, lane = tid & 63, wid = tid >> 6;
  const int l15 = lane & 15, g = lane >> 4;
  const int r0 = blockIdx.x * 64 + wid * 16;

  for (int i = 0; i < 64; ++i) {
    int idx = i * 256 + tid;
    int k = idx >> 7, n = idx & 127;
    int cs = (k >> 3) ^ (n & 7);
    wt[n * 128 + cs * 8 + (k & 7)] = f2bf(Wo[idx]);
  }

  short8 af[4];
  const unsigned short* ap = Ag + (r0 + l15) * 128 + g * 8;
#pragma unroll
  for (int kt = 0; kt < 4; ++kt) af[kt] = *(const short8*)(ap + kt * 32);

  float bias[8];
#pragma unroll
  for (int nt = 0; nt < 8; ++nt) bias[nt] = bo[nt * 16 + l15];

  __syncthreads();

  f32x4 acc[8];
#pragma unroll
  for (int nt = 0; nt < 8; ++nt) acc[nt] = (f32x4){0.f, 0.f, 0.f, 0.f};
#pragma unroll
  for (int nt = 0; nt < 8; ++nt) {
    int n = nt * 16 + l15;
#pragma unroll
    for (int ks = 0; ks < 4; ++ks) {
      int cs = (ks * 4 + g) ^ (n & 7);
      short8 bf = *(const short8*)&wt[n * 128 + cs * 8];
      acc[nt] = MFMA16(af[ks], bf, acc[nt]);
    }
  }
#pragma unroll
  for (int nt = 0; nt < 8; ++nt) {
    int col = nt * 16 + l15;
#pragma unroll
    for (int r = 0; r < 4; ++r)
      out[(r0 + g * 4 + r) * 128 + col] = acc[nt][r] + bias[nt];
  }
}

// ---------------------------------------------------------------------------
extern "C" void kernel_launch(void* const* d_in, const int* in_sizes, int n_in,
                              void* d_out, int out_size, void* d_ws, size_t ws_size,
                              hipStream_t stream) {
  const float* x  = (const float*)d_in[0];
  const float* Wq = (const float*)d_in[1];
  const float* bq = (const float*)d_in[2];
  const float* Wk = (const float*)d_in[3];
  const float* bk = (const float*)d_in[4];
  const float* Wv = (const float*)d_in[5];
  const float* bv = (const float*)d_in[6];
  const float* Wo = (const float*)d_in[7];
  const float* bo = (const float*)d_in[8];

  const int NTOK = 4 * 4096;               // B*S
  unsigned short* Qg  = (unsigned short*)d_ws;
  unsigned short* Kg  = Qg  + NTOK * 128;
  unsigned short* Vtg = Kg  + NTOK * 128;
  unsigned short* Ag  = Vtg + NTOK * 128;  // total 16 MB of d_ws

  k_proj<<<256, 256, 0, stream>>>(x, Wq, bq, Wk, bk, Wv, bv, Qg, Kg, Vtg);
  k_attn<<<256, 256, 0, stream>>>(Qg, Kg, Vtg, Ag);
  k_out<<<256, 256, 0, stream>>>(Ag, Wo, bo, (float*)d_out);
}

// Round 2
// 112.169 us; speedup vs baseline: 1.6414x; 1.6414x over previous
//
#include <hip/hip_runtime.h>
#include <stdint.h>

typedef __attribute__((ext_vector_type(8))) short short8;
typedef __attribute__((ext_vector_type(4))) float f32x4;

#define MFMA16(a, b, c) __builtin_amdgcn_mfma_f32_16x16x32_bf16((a), (b), (c), 0, 0, 0)

typedef __attribute__((address_space(1))) const void GVoid;
typedef __attribute__((address_space(3))) void LVoid;
#define GLDS16(g, l) __builtin_amdgcn_global_load_lds((GVoid*)(g), (LVoid*)(l), 16, 0, 0)

#define L2E 1.4426950408889634f

__device__ __forceinline__ unsigned short f2bf(float f) {
  unsigned int u = __builtin_bit_cast(unsigned int, f);
  u += 0x7fffu + ((u >> 16) & 1u);   // RNE (finite values only)
  return (unsigned short)(u >> 16);
}

// ---------------------------------------------------------------------------
// Kernel 1: Q/K/V projections. Q pre-scaled by 1/sqrt(128). V stored transposed.
//   Qg,Kg: bf16 [B*S][128] row-major.  Vtg: bf16 [B][128][S].
// ---------------------------------------------------------------------------
__global__ __launch_bounds__(256) void k_proj(
    const float* __restrict__ x,
    const float* __restrict__ Wq, const float* __restrict__ bq,
    const float* __restrict__ Wk, const float* __restrict__ bk,
    const float* __restrict__ Wv, const float* __restrict__ bv,
    unsigned short* __restrict__ Qg, unsigned short* __restrict__ Kg,
    unsigned short* __restrict__ Vtg)
{
  __shared__ __align__(16) unsigned short wt[128 * 128];  // swizzled W^T, 32KB
  const int tid  = threadIdx.x;
  const int lane = tid & 63;
  const int wid  = tid >> 6;
  const int l15  = lane & 15;
  const int g    = lane >> 4;
  const int r0   = blockIdx.x * 64 + wid * 16;

  short8 af[4];
  {
    const float* xp = x + (r0 + l15) * 128 + g * 8;
#pragma unroll
    for (int kt = 0; kt < 4; ++kt) {
      float4 v0 = *(const float4*)(xp + kt * 32);
      float4 v1 = *(const float4*)(xp + kt * 32 + 4);
      short8 a;
      a[0] = (short)f2bf(v0.x); a[1] = (short)f2bf(v0.y);
      a[2] = (short)f2bf(v0.z); a[3] = (short)f2bf(v0.w);
      a[4] = (short)f2bf(v1.x); a[5] = (short)f2bf(v1.y);
      a[6] = (short)f2bf(v1.z); a[7] = (short)f2bf(v1.w);
      af[kt] = a;
    }
  }

  const float* Ws[3] = {Wq, Wk, Wv};
  const float* bs[3] = {bq, bk, bv};

  for (int wI = 0; wI < 3; ++wI) {
    __syncthreads();
    const float* W = Ws[wI];
    for (int i = 0; i < 64; ++i) {
      int idx = i * 256 + tid;
      int k = idx >> 7, n = idx & 127;
      int cs = (k >> 3) ^ (n & 7);
      wt[n * 128 + cs * 8 + (k & 7)] = f2bf(W[idx]);
    }
    __syncthreads();

    float bias[8];
#pragma unroll
    for (int nt = 0; nt < 8; ++nt) bias[nt] = bs[wI][nt * 16 + l15];

    f32x4 acc[8];
#pragma unroll
    for (int nt = 0; nt < 8; ++nt) acc[nt] = (f32x4){0.f, 0.f, 0.f, 0.f};

#pragma unroll
    for (int nt = 0; nt < 8; ++nt) {
      const int n = nt * 16 + l15;
#pragma unroll
      for (int ks = 0; ks < 4; ++ks) {
        int cs = (ks * 4 + g) ^ (n & 7);
        short8 bf = *(const short8*)&wt[n * 128 + cs * 8];
        acc[nt] = MFMA16(af[ks], bf, acc[nt]);
      }
    }

    if (wI < 2) {
      unsigned short* Og = (wI == 0) ? Qg : Kg;
      const float sc = (wI == 0) ? 0.08838834764831845f : 1.0f;  // 1/sqrt(128)
#pragma unroll
      for (int nt = 0; nt < 8; ++nt) {
        int col = nt * 16 + l15;
#pragma unroll
        for (int r = 0; r < 4; ++r) {
          int m = r0 + g * 4 + r;
          Og[m * 128 + col] = f2bf((acc[nt][r] + bias[nt]) * sc);
        }
      }
    } else {
#pragma unroll
      for (int nt = 0; nt < 8; ++nt) {
        int col = nt * 16 + l15;
        int m0 = r0 + g * 4;
        int bb = m0 >> 12, s0 = m0 & 4095;
        ushort4 pk;
        pk.x = f2bf(acc[nt][0] + bias[nt]);
        pk.y = f2bf(acc[nt][1] + bias[nt]);
        pk.z = f2bf(acc[nt][2] + bias[nt]);
        pk.w = f2bf(acc[nt][3] + bias[nt]);
        *(ushort4*)&Vtg[(bb * 128 + col) * 4096 + s0] = pk;
      }
    }
  }
}

// ---------------------------------------------------------------------------
// Kernel 2: flash attention, 8 waves (512 thr) per block, 1 block/CU.
//   wave = (qsub = wid>>1 -> 16 q-rows, half = wid&1 -> KV range of 2048).
// Swapped QK^T (mfma(K,Q)) -> in-register softmax (lane l15 = q).
// KVBLK=64 double-buffered global_load_lds; in-LDS split-KV merge (2 halves).
// LDS: K [2half][2dbuf][64][128] 64KB | Vt same 64KB | P [8 wave][16][128B] 16KB
// ---------------------------------------------------------------------------
#define KOFF 0
#define VOFF 65536
#define POFF 131072

__global__ __launch_bounds__(512, 2) void k_attn(
    const unsigned short* __restrict__ Qg,
    const unsigned short* __restrict__ Kg,
    const unsigned short* __restrict__ Vtg,
    unsigned short* __restrict__ Ag)
{
  __shared__ __align__(16) char smem[147456];
  const int tid = threadIdx.x, lane = tid & 63, wid = tid >> 6;
  const int l15 = lane & 15, g = lane >> 4;
  const int sw = (l15 & 7) << 4;           // P-region row swizzle (bytes)
  // XCD-aware mapping: batch b pinned to XCD pair {2b,2b+1}
  const int p = blockIdx.x;
  const int b = (p & 7) >> 1;
  const int qt = ((p >> 3) << 1) | (p & 1);
  const int qsub = wid >> 1, half = wid & 1;
  const int q0 = qt * 64 + qsub * 16;

  // Q fragments (pre-scaled by 1/sqrt(128)); lane l15 = q row, k = g*8+kt*32
  short8 qf[4];
  {
    const unsigned short* qp = Qg + (b * 4096 + q0 + l15) * 128 + g * 8;
#pragma unroll
    for (int kt = 0; kt < 4; ++kt) qf[kt] = *(const short8*)(qp + kt * 32);
  }

  f32x4 O[8];
#pragma unroll
  for (int nt = 0; nt < 8; ++nt) O[nt] = (f32x4){0.f, 0.f, 0.f, 0.f};
  float mS = -3.0e38f, lS = 0.f;

  char* const pbase = smem + POFF + wid * 2048 + l15 * 128;

  // 4 tiles/iter: {K h0, K h1, V h0, V h1}; each staged by a 2-wave team.
  auto stageAll = [&](int t, int d) {
    const int tg = wid >> 1, w2 = wid & 1;
    if (tg < 2) {
      const int h = tg;
      const int kv0 = h * 2048 + t * 64;
#pragma unroll
      for (int i = 0; i < 8; ++i) {
        int slot = i * 128 + w2 * 64 + lane;
        int r = slot >> 4, c = slot & 15;
        const unsigned short* src = Kg + (b * 4096 + kv0 + r) * 128 + ((c ^ (r & 7)) * 8);
        char* dstu = smem + KOFF + (h * 2 + d) * 16384 + (i * 128 + w2 * 64) * 16;
        GLDS16(src, dstu);
      }
    } else {
      const int h = tg - 2;
      const int kv0 = h * 2048 + t * 64;
#pragma unroll
      for (int i = 0; i < 8; ++i) {
        int slot = i * 128 + w2 * 64 + lane;
        int dr = slot >> 3, c = slot & 7;
        const unsigned short* src = Vtg + (b * 128 + dr) * 4096 + kv0 + ((c ^ (dr & 7)) * 8);
        char* dstu = smem + VOFF + (h * 2 + d) * 16384 + (i * 128 + w2 * 64) * 16;
        GLDS16(src, dstu);
      }
    }
  };

  stageAll(0, 0);
  __syncthreads();

  int cur = 0;
  for (int t = 0; t < 32; ++t) {
    if (t + 1 < 32) stageAll(t + 1, cur ^ 1);   // async prefetch of next tile

    // ---- QK^T swapped: S^T[64 kv][16 q]; lane l15 = q, holds kv=ct*16+g*4+r
    const char* kbase = smem + KOFF + (half * 2 + cur) * 16384;
    f32x4 sT[4];
#pragma unroll
    for (int ct = 0; ct < 4; ++ct) sT[ct] = (f32x4){0.f, 0.f, 0.f, 0.f};
    __builtin_amdgcn_s_setprio(1);
#pragma unroll
    for (int ct = 0; ct < 4; ++ct) {
      const char* krow = kbase + (ct * 16 + l15) * 256;
#pragma unroll
      for (int ks = 0; ks < 4; ++ks) {
        int cs = (ks * 4 + g) ^ (l15 & 7);
        short8 kf = *(const short8*)(krow + cs * 16);
        sT[ct] = MFMA16(kf, qf[ks], sT[ct]);
      }
    }
    __builtin_amdgcn_s_setprio(0);

    // ---- online softmax, fully per-lane (q = l15), 2 shuffles per reduce ----
    float mx = fmaxf(fmaxf(fmaxf(sT[0][0], sT[0][1]), fmaxf(sT[0][2], sT[0][3])),
                     fmaxf(fmaxf(sT[1][0], sT[1][1]), fmaxf(sT[1][2], sT[1][3])));
    mx = fmaxf(mx, fmaxf(fmaxf(fmaxf(sT[2][0], sT[2][1]), fmaxf(sT[2][2], sT[2][3])),
                         fmaxf(fmaxf(sT[3][0], sT[3][1]), fmaxf(sT[3][2], sT[3][3]))));
    mx = fmaxf(mx, __shfl_xor(mx, 16, 64));
    mx = fmaxf(mx, __shfl_xor(mx, 32, 64));
    float mnew = fmaxf(mS, mx);
    float fsc = exp2f((mS - mnew) * L2E);
    mS = mnew;

    float ts = 0.f;
#pragma unroll
    for (int ct = 0; ct < 4; ++ct) {
      float p0 = exp2f((sT[ct][0] - mnew) * L2E);
      float p1 = exp2f((sT[ct][1] - mnew) * L2E);
      float p2 = exp2f((sT[ct][2] - mnew) * L2E);
      float p3 = exp2f((sT[ct][3] - mnew) * L2E);
      ts += (p0 + p1) + (p2 + p3);
      ushort4 pk;
      pk.x = f2bf(p0); pk.y = f2bf(p1); pk.z = f2bf(p2); pk.w = f2bf(p3);
      *(ushort4*)(pbase + ((ct * 32 + g * 8) ^ sw)) = pk;   // conflict-free
    }
    ts += __shfl_xor(ts, 16, 64);
    ts += __shfl_xor(ts, 32, 64);
    lS = lS * fsc + ts;

    // redistribute fsc from q-space (l15) to O-row space (g*4+r)
    float fr0 = __shfl(fsc, g * 4 + 0, 64);
    float fr1 = __shfl(fsc, g * 4 + 1, 64);
    float fr2 = __shfl(fsc, g * 4 + 2, 64);
    float fr3 = __shfl(fsc, g * 4 + 3, 64);
#pragma unroll
    for (int nt = 0; nt < 8; ++nt) {
      O[nt][0] *= fr0; O[nt][1] *= fr1; O[nt][2] *= fr2; O[nt][3] *= fr3;
    }

    // ---- PV: O[16 q][128 d] += P[16 q][64 kv] * V[64 kv][128 d] ----
    short8 pa0 = *(const short8*)(pbase + ((g * 16) ^ sw));
    short8 pa1 = *(const short8*)(pbase + ((64 + g * 16) ^ sw));
    const char* vbase = smem + VOFF + (half * 2 + cur) * 16384;
    __builtin_amdgcn_s_setprio(1);
#pragma unroll
    for (int nt = 0; nt < 8; ++nt) {
      const char* vrow = vbase + (nt * 16 + l15) * 128;
      int cs0 = g ^ (l15 & 7);
      int cs1 = (4 + g) ^ (l15 & 7);
      short8 vf0 = *(const short8*)(vrow + cs0 * 16);
      O[nt] = MFMA16(pa0, vf0, O[nt]);
      short8 vf1 = *(const short8*)(vrow + cs1 * 16);
      O[nt] = MFMA16(pa1, vf1, O[nt]);
    }
    __builtin_amdgcn_s_setprio(0);

    __syncthreads();   // drains staging loads + protects dbuf swap
    cur ^= 1;
  }

  // ---- split-KV merge across the 2 half-waves of each qsub ----
  float* mo  = (float*)smem;             // [4 qsub][16][128] fp32 = 32KB
  float* mlp = (float*)(smem + 32768);   // [64 q][2] (m, l)
  if (half == 1) {
#pragma unroll
    for (int nt = 0; nt < 8; ++nt) {
      int col = nt * 16 + l15;
#pragma unroll
      for (int r = 0; r < 4; ++r)
        mo[(qsub * 16 + g * 4 + r) * 128 + col] = O[nt][r];
    }
    if (g == 0) {
      mlp[(qsub * 16 + l15) * 2 + 0] = mS;
      mlp[(qsub * 16 + l15) * 2 + 1] = lS;
    }
  }
  __syncthreads();
  if (half == 0) {
    float m2 = mlp[(qsub * 16 + l15) * 2 + 0];
    float l2 = mlp[(qsub * 16 + l15) * 2 + 1];
    float mm = fmaxf(mS, m2);
    float a1 = exp2f((mS - mm) * L2E);
    float a2 = exp2f((m2 - mm) * L2E);
    float den = lS * a1 + l2 * a2;
    float c1 = a1 / den, c2 = a2 / den;
    float cr1[4], cr2[4];
#pragma unroll
    for (int r = 0; r < 4; ++r) {
      cr1[r] = __shfl(c1, g * 4 + r, 64);
      cr2[r] = __shfl(c2, g * 4 + r, 64);
    }
#pragma unroll
    for (int nt = 0; nt < 8; ++nt) {
      int col = nt * 16 + l15;
#pragma unroll
      for (int r = 0; r < 4; ++r) {
        int row = qsub * 16 + g * 4 + r;
        float o = O[nt][r] * cr1[r] + mo[row * 128 + col] * cr2[r];
        Ag[(b * 4096 + qt * 64 + row) * 128 + col] = f2bf(o);
      }
    }
  }
}

// ---------------------------------------------------------------------------
// Kernel 3: out = attended @ Wo + bo  (fp32 output)
// ---------------------------------------------------------------------------
__global__ __launch_bounds__(256) void k_out(
    const unsigned short* __restrict__ Ag,
    const float* __restrict__ Wo, const float* __restrict__ bo,
    float* __restrict__ out)
{
  __shared__ __align__(16) unsigned short wt[128 * 128];
  const int tid = threadIdx.x, lane = tid & 63, wid = tid >> 6;
  const int l15 = lane & 15, g = lane >> 4;
  const int r0 = blockIdx.x * 64 + wid * 16;

  for (int i = 0; i < 64; ++i) {
    int idx = i * 256 + tid;
    int k = idx >> 7, n = idx & 127;
    int cs = (k >> 3) ^ (n & 7);
    wt[n * 128 + cs * 8 + (k & 7)] = f2bf(Wo[idx]);
  }

  short8 af[4];
  const unsigned short* ap = Ag + (r0 + l15) * 128 + g * 8;
#pragma unroll
  for (int kt = 0; kt < 4; ++kt) af[kt] = *(const short8*)(ap + kt * 32);

  float bias[8];
#pragma unroll
  for (int nt = 0; nt < 8; ++nt) bias[nt] = bo[nt * 16 + l15];

  __syncthreads();

  f32x4 acc[8];
#pragma unroll
  for (int nt = 0; nt < 8; ++nt) acc[nt] = (f32x4){0.f, 0.f, 0.f, 0.f};
#pragma unroll
  for (int nt = 0; nt < 8; ++nt) {
    int n = nt * 16 + l15;
#pragma unroll
    for (int ks = 0; ks < 4; ++ks) {
      int cs = (ks * 4 + g) ^ (n & 7);
      short8 bf = *(const short8*)&wt[n * 128 + cs * 8];
      acc[nt] = MFMA16(af[ks], bf, acc[nt]);
    }
  }
#pragma unroll
  for (int nt = 0; nt < 8; ++nt) {
    int col = nt * 16 + l15;
#pragma unroll
    for (int r = 0; r < 4; ++r)
      out[(r0 + g * 4 + r) * 128 + col] = acc[nt][r] + bias[nt];
  }
}

// ---------------------------------------------------------------------------
extern "C" void kernel_launch(void* const* d_in, const int* in_sizes, int n_in,
                              void* d_out, int out_size, void* d_ws, size_t ws_size,
                              hipStream_t stream) {
  const float* x  = (const float*)d_in[0];
  const float* Wq = (const float*)d_in[1];
  const float* bq = (const float*)d_in[2];
  const float* Wk = (const float*)d_in[3];
  const float* bk = (const float*)d_in[4];
  const float* Wv = (const float*)d_in[5];
  const float* bv = (const float*)d_in[6];
  const float* Wo = (const float*)d_in[7];
  const float* bo = (const float*)d_in[8];

  const int NTOK = 4 * 4096;               // B*S
  unsigned short* Qg  = (unsigned short*)d_ws;
  unsigned short* Kg  = Qg  + NTOK * 128;
  unsigned short* Vtg = Kg  + NTOK * 128;
  unsigned short* Ag  = Vtg + NTOK * 128;  // total 16 MB of d_ws

  k_proj<<<256, 256, 0, stream>>>(x, Wq, bq, Wk, bk, Wv, bv, Qg, Kg, Vtg);
  k_attn<<<256, 512, 0, stream>>>(Qg, Kg, Vtg, Ag);
  k_out<<<256, 256, 0, stream>>>(Ag, Wo, bo, (float*)d_out);
}

// Round 4
// 99.953 us; speedup vs baseline: 1.8421x; 1.1222x over previous
//
#include <hip/hip_runtime.h>
#include <stdint.h>

typedef __attribute__((ext_vector_type(8))) short short8;
typedef __attribute__((ext_vector_type(4))) float f32x4;
typedef __attribute__((ext_vector_type(16))) float f32x16;
typedef __attribute__((ext_vector_type(4))) int i32x4;
typedef __attribute__((ext_vector_type(2))) int i32x2;

#define MFMA16(a, b, c) __builtin_amdgcn_mfma_f32_16x16x32_bf16((a), (b), (c), 0, 0, 0)
#define MFMA32(a, b, c) __builtin_amdgcn_mfma_f32_32x32x16_bf16((a), (b), (c), 0, 0, 0)

typedef __attribute__((address_space(1))) const void GVoid;
typedef __attribute__((address_space(3))) void LVoid;
#define GLDS16(g, l) __builtin_amdgcn_global_load_lds((GVoid*)(g), (LVoid*)(l), 16, 0, 0)

#define L2E 1.4426950408889634f

__device__ __forceinline__ unsigned short f2bf(float f) {
  unsigned int u = __builtin_bit_cast(unsigned int, f);
  u += 0x7fffu + ((u >> 16) & 1u);   // RNE (finite values only)
  return (unsigned short)(u >> 16);
}

// permlane32_swap via builtin: returns {new_a, new_b}; results are
// simultaneously live -> backend must use distinct registers (the inline-asm
// "+v","+v" form could coalesce both operands onto ONE register when fed the
// same value -> self-swap corruption; that was R3's bug).
__device__ __forceinline__ i32x2 pls(int a, int b) {
  return __builtin_amdgcn_permlane32_swap(a, b, false, false);
}
__device__ __forceinline__ float fasf(int x) { return __builtin_bit_cast(float, x); }
__device__ __forceinline__ int iasi(float x) { return __builtin_bit_cast(int, x); }

__device__ __forceinline__ int cvtpk(float lo, float hi) {
  int d;
  asm("v_cvt_pk_bf16_f32 %0, %1, %2" : "=v"(d) : "v"(lo), "v"(hi));
  return d;
}

// ---------------------------------------------------------------------------
// Kernel 1: Q/K/V projections. Q pre-scaled by 1/sqrt(128). V stored transposed.
//   Qg,Kg: bf16 [B*S][128] row-major.  Vtg: bf16 [B][128][S].
// ---------------------------------------------------------------------------
__global__ __launch_bounds__(256) void k_proj(
    const float* __restrict__ x,
    const float* __restrict__ Wq, const float* __restrict__ bq,
    const float* __restrict__ Wk, const float* __restrict__ bk,
    const float* __restrict__ Wv, const float* __restrict__ bv,
    unsigned short* __restrict__ Qg, unsigned short* __restrict__ Kg,
    unsigned short* __restrict__ Vtg)
{
  __shared__ __align__(16) unsigned short wt[128 * 128];  // swizzled W^T, 32KB
  const int tid  = threadIdx.x;
  const int lane = tid & 63;
  const int wid  = tid >> 6;
  const int l15  = lane & 15;
  const int g    = lane >> 4;
  const int r0   = blockIdx.x * 64 + wid * 16;

  short8 af[4];
  {
    const float* xp = x + (r0 + l15) * 128 + g * 8;
#pragma unroll
    for (int kt = 0; kt < 4; ++kt) {
      float4 v0 = *(const float4*)(xp + kt * 32);
      float4 v1 = *(const float4*)(xp + kt * 32 + 4);
      short8 a;
      a[0] = (short)f2bf(v0.x); a[1] = (short)f2bf(v0.y);
      a[2] = (short)f2bf(v0.z); a[3] = (short)f2bf(v0.w);
      a[4] = (short)f2bf(v1.x); a[5] = (short)f2bf(v1.y);
      a[6] = (short)f2bf(v1.z); a[7] = (short)f2bf(v1.w);
      af[kt] = a;
    }
  }

  const float* Ws[3] = {Wq, Wk, Wv};
  const float* bs[3] = {bq, bk, bv};

  for (int wI = 0; wI < 3; ++wI) {
    __syncthreads();
    const float* W = Ws[wI];
    for (int i = 0; i < 64; ++i) {
      int idx = i * 256 + tid;
      int k = idx >> 7, n = idx & 127;
      int cs = (k >> 3) ^ (n & 7);
      wt[n * 128 + cs * 8 + (k & 7)] = f2bf(W[idx]);
    }
    __syncthreads();

    float bias[8];
#pragma unroll
    for (int nt = 0; nt < 8; ++nt) bias[nt] = bs[wI][nt * 16 + l15];

    f32x4 acc[8];
#pragma unroll
    for (int nt = 0; nt < 8; ++nt) acc[nt] = (f32x4){0.f, 0.f, 0.f, 0.f};

#pragma unroll
    for (int nt = 0; nt < 8; ++nt) {
      const int n = nt * 16 + l15;
#pragma unroll
      for (int ks = 0; ks < 4; ++ks) {
        int cs = (ks * 4 + g) ^ (n & 7);
        short8 bf = *(const short8*)&wt[n * 128 + cs * 8];
        acc[nt] = MFMA16(af[ks], bf, acc[nt]);
      }
    }

    if (wI < 2) {
      unsigned short* Og = (wI == 0) ? Qg : Kg;
      const float sc = (wI == 0) ? 0.08838834764831845f : 1.0f;  // 1/sqrt(128)
#pragma unroll
      for (int nt = 0; nt < 8; ++nt) {
        int col = nt * 16 + l15;
#pragma unroll
        for (int r = 0; r < 4; ++r) {
          int m = r0 + g * 4 + r;
          Og[m * 128 + col] = f2bf((acc[nt][r] + bias[nt]) * sc);
        }
      }
    } else {
#pragma unroll
      for (int nt = 0; nt < 8; ++nt) {
        int col = nt * 16 + l15;
        int m0 = r0 + g * 4;
        int bb = m0 >> 12, s0 = m0 & 4095;
        ushort4 pk;
        pk.x = f2bf(acc[nt][0] + bias[nt]);
        pk.y = f2bf(acc[nt][1] + bias[nt]);
        pk.z = f2bf(acc[nt][2] + bias[nt]);
        pk.w = f2bf(acc[nt][3] + bias[nt]);
        *(ushort4*)&Vtg[(bb * 128 + col) * 4096 + s0] = pk;
      }
    }
  }
}

// ---------------------------------------------------------------------------
// Kernel 2: flash attention, 4 waves (256 thr) per block, 2 blocks/CU.
// Block = 32 q-rows; wave w owns kv range [w*1024, w*1024+1024), KVBLK=32.
// Swapped QK^T with 32x32x16 MFMA: lane = q (lane&31), regs = kv.
// Softmax + P->A-frag fully in registers (cvt_pk + permlane32_swap).
// Wave-private single-buffered LDS K/V regions, zero barriers in loop.
// LDS: [4 waves][K 8KB | Vt 8KB] = 64KB; tail: ml 768B, cbuf 512B, rbuf 512B
// ---------------------------------------------------------------------------
#define MLOFF 65536
#define CBUF  66304
#define RBUF  66816

__global__ __launch_bounds__(256, 2) void k_attn(
    const unsigned short* __restrict__ Qg,
    const unsigned short* __restrict__ Kg,
    const unsigned short* __restrict__ Vtg,
    unsigned short* __restrict__ Ag)
{
  __shared__ __align__(16) char smem[67584];
  const int tid = threadIdx.x, lane = tid & 63, wid = tid >> 6;
  const int rr = lane & 31, hi = lane >> 5;
  // XCD-aware: batch b pinned to XCD pair {2b,2b+1}
  const int p = blockIdx.x;
  const int b = (p & 7) >> 1;
  const int qt = ((p >> 3) << 1) | (p & 1);
  const int q0 = qt * 32;
  const int kvb0 = wid * 1024;

  // Q fragments (pre-scaled): B-operand, col=q=rr, k = kt*16 + hi*8 + j
  short8 qf[8];
  {
    const unsigned short* qp = Qg + (b * 4096 + q0 + rr) * 128 + hi * 8;
#pragma unroll
    for (int kt = 0; kt < 8; ++kt) qf[kt] = *(const short8*)(qp + kt * 16);
  }

  char* const kreg = smem + wid * 16384;
  char* const vreg = kreg + 8192;

  // staging source element-offsets (pre-swizzled so linear GLDS dest = swizzled image)
  int koff[8], voff[8];
#pragma unroll
  for (int i = 0; i < 8; ++i) {
    int D = i * 1024 + lane * 16;
    int krow = D >> 8, kcp = (D >> 4) & 15;
    koff[i] = (b * 4096 + kvb0 + krow) * 128 + (kcp ^ (krow & 15)) * 8;
    int dp = D >> 7, vcp = (D >> 4) & 7;
    int cl = vcp ^ (dp & 7);
    voff[i] = (b * 128 + dp * 2 + (cl >> 2)) * 4096 + kvb0 + ((cl >> 1) & 1) * 16 + (cl & 1) * 8;
  }
  // fragment read LDS byte-offsets (constant across iterations)
  int kfo[8];
#pragma unroll
  for (int kt = 0; kt < 8; ++kt) kfo[kt] = rr * 256 + (((kt * 2 + hi) ^ (rr & 15)) << 4);
  int vfo[2];
#pragma unroll
  for (int kt = 0; kt < 2; ++kt)
    vfo[kt] = (rr >> 1) * 128 + ((((rr & 1) * 4 + kt * 2 + hi) ^ ((rr >> 1) & 7)) << 4);

  // prologue stage t=0
#pragma unroll
  for (int i = 0; i < 8; ++i) GLDS16(Kg + koff[i], kreg + i * 1024 + lane * 16);
#pragma unroll
  for (int i = 0; i < 8; ++i) GLDS16(Vtg + voff[i], vreg + i * 1024 + lane * 16);

  f32x16 O[4];
#pragma unroll
  for (int dt = 0; dt < 4; ++dt)
#pragma unroll
    for (int j = 0; j < 16; ++j) O[dt][j] = 0.f;
  float mS = -3.0e38f, lS = 0.f;

  for (int t = 0; t < 32; ++t) {
    asm volatile("s_waitcnt vmcnt(0)" ::: "memory");     // tile t resident
    short8 kf[8];
#pragma unroll
    for (int kt = 0; kt < 8; ++kt) kf[kt] = *(const short8*)(kreg + kfo[kt]);
    short8 vf[2][4];
#pragma unroll
    for (int kt = 0; kt < 2; ++kt)
#pragma unroll
      for (int dt = 0; dt < 4; ++dt)
        vf[kt][dt] = *(const short8*)(vreg + vfo[kt] + dt * 2048);
    asm volatile("s_waitcnt lgkmcnt(0)" ::: "memory");   // frags in regs
    __builtin_amdgcn_sched_barrier(0);                   // rule 18
    if (t < 31) {                                        // prefetch t+1 into own region
      const int tk = (t + 1) * 4096, tv = (t + 1) * 32;
#pragma unroll
      for (int i = 0; i < 8; ++i) GLDS16(Kg + koff[i] + tk, kreg + i * 1024 + lane * 16);
#pragma unroll
      for (int i = 0; i < 8; ++i) GLDS16(Vtg + voff[i] + tv, vreg + i * 1024 + lane * 16);
    }

    // ---- QK^T swapped: D[kv=regs][q=lane&31] ----
    f32x16 sT = {0,0,0,0,0,0,0,0,0,0,0,0,0,0,0,0};
    __builtin_amdgcn_s_setprio(1);
#pragma unroll
    for (int kt = 0; kt < 8; ++kt) sT = MFMA32(kf[kt], qf[kt], sT);
    __builtin_amdgcn_s_setprio(0);

    // ---- online softmax, in-register; kv row of reg r = (r&3)+8*(r>>2)+4*hi ----
    float pm = fmaxf(fmaxf(fmaxf(sT[0], sT[1]), fmaxf(sT[2], sT[3])),
                     fmaxf(fmaxf(sT[4], sT[5]), fmaxf(sT[6], sT[7])));
    pm = fmaxf(pm, fmaxf(fmaxf(fmaxf(sT[8], sT[9]), fmaxf(sT[10], sT[11])),
                         fmaxf(fmaxf(sT[12], sT[13]), fmaxf(sT[14], sT[15]))));
    { i32x2 r = pls(iasi(pm), iasi(pm)); pm = fmaxf(fasf(r[0]), fasf(r[1])); }

    if (!__all(pm - mS <= 8.0f)) {          // defer-max (THR=8)
      float mnew = fmaxf(mS, pm);
      float fsc = exp2f((mS - mnew) * L2E);
      mS = mnew;
      lS *= fsc;
      // redistribute fsc from lane-q to reg-rows via wave-private LDS broadcast
      if (hi == 0) *(float*)(smem + RBUF + wid * 128 + rr * 4) = fsc;
      f32x4 fr[4];
#pragma unroll
      for (int i = 0; i < 4; ++i)
        fr[i] = *(const f32x4*)(smem + RBUF + wid * 128 + i * 32 + hi * 16);
#pragma unroll
      for (int dt = 0; dt < 4; ++dt)
#pragma unroll
        for (int i = 0; i < 4; ++i)
#pragma unroll
          for (int j = 0; j < 4; ++j) O[dt][i * 4 + j] *= fr[i][j];
    }

    const float mL = mS * L2E;
    float pv[16]; float ts = 0.f;
#pragma unroll
    for (int r = 0; r < 16; ++r) {
      pv[r] = exp2f(sT[r] * L2E - mL);
      ts += pv[r];
    }
    { i32x2 r = pls(iasi(ts), iasi(ts)); ts = fasf(r[0]) + fasf(r[1]); }
    lS += ts;

    // ---- P -> PV A-fragments fully in registers (T12) ----
    int dw[8];
#pragma unroll
    for (int m = 0; m < 8; ++m) dw[m] = cvtpk(pv[2 * m], pv[2 * m + 1]);
    i32x2 ra = pls(dw[0], dw[2]);
    i32x2 rb = pls(dw[1], dw[3]);
    i32x2 rc = pls(dw[4], dw[6]);
    i32x2 rd = pls(dw[5], dw[7]);
    i32x4 w0 = {ra[0], rb[0], ra[1], rb[1]};
    i32x4 w1 = {rc[0], rd[0], rc[1], rd[1]};
    short8 pa0 = __builtin_bit_cast(short8, w0);
    short8 pa1 = __builtin_bit_cast(short8, w1);

    // ---- PV: O[q][d] += P[q][kv] * V[kv][d] ----
    __builtin_amdgcn_s_setprio(1);
#pragma unroll
    for (int dt = 0; dt < 4; ++dt) {
      O[dt] = MFMA32(pa0, vf[0][dt], O[dt]);
      O[dt] = MFMA32(pa1, vf[1][dt], O[dt]);
    }
    __builtin_amdgcn_s_setprio(0);
  }

  // ---- in-LDS merge of the 4 kv-splits ----
  if (wid > 0) {
#pragma unroll
    for (int dt = 0; dt < 4; ++dt)
#pragma unroll
      for (int i = 0; i < 4; ++i) {
        f32x4 s = {O[dt][4 * i], O[dt][4 * i + 1], O[dt][4 * i + 2], O[dt][4 * i + 3]};
        *(f32x4*)(kreg + (dt * 4 + i) * 1024 + lane * 16) = s;
      }
    if (hi == 0)
      *(float2*)(smem + MLOFF + (wid - 1) * 256 + rr * 8) = make_float2(mS, lS);
  }
  __syncthreads();
  if (wid == 0) {
    float mh[4], lh[4];
    mh[0] = mS; lh[0] = lS;
#pragma unroll
    for (int h = 1; h < 4; ++h) {
      float2 ml = *(const float2*)(smem + MLOFF + (h - 1) * 256 + rr * 8);
      mh[h] = ml.x; lh[h] = ml.y;
    }
    float M = fmaxf(fmaxf(mh[0], mh[1]), fmaxf(mh[2], mh[3]));
    float c[4], L = 0.f;
#pragma unroll
    for (int h = 0; h < 4; ++h) { c[h] = exp2f((mh[h] - M) * L2E); L += c[h] * lh[h]; }
    float iL = 1.0f / L;
    if (hi == 0) {
#pragma unroll
      for (int h = 0; h < 4; ++h) *(float*)(smem + CBUF + h * 128 + rr * 4) = c[h];
      *(float*)(smem + RBUF + rr * 4) = iL;
    }
    f32x4 cr[4][4], ir[4];
#pragma unroll
    for (int i = 0; i < 4; ++i) {
#pragma unroll
      for (int h = 0; h < 4; ++h)
        cr[h][i] = *(const f32x4*)(smem + CBUF + h * 128 + i * 32 + hi * 16);
      ir[i] = *(const f32x4*)(smem + RBUF + i * 32 + hi * 16);
    }
    unsigned short* og = Ag + (size_t)(b * 4096 + q0) * 128;
#pragma unroll
    for (int dt = 0; dt < 4; ++dt)
#pragma unroll
      for (int i = 0; i < 4; ++i) {
        f32x4 o1 = *(const f32x4*)(smem + 1 * 16384 + (dt * 4 + i) * 1024 + lane * 16);
        f32x4 o2 = *(const f32x4*)(smem + 2 * 16384 + (dt * 4 + i) * 1024 + lane * 16);
        f32x4 o3 = *(const f32x4*)(smem + 3 * 16384 + (dt * 4 + i) * 1024 + lane * 16);
#pragma unroll
        for (int j = 0; j < 4; ++j) {
          float v = (cr[0][i][j] * O[dt][4 * i + j] + cr[1][i][j] * o1[j] +
                     cr[2][i][j] * o2[j] + cr[3][i][j] * o3[j]) * ir[i][j];
          int row = j + 8 * i + 4 * hi;
          og[row * 128 + dt * 32 + rr] = f2bf(v);
        }
      }
  }
}

// ---------------------------------------------------------------------------
// Kernel 3: out = attended @ Wo + bo  (fp32 output)
// ---------------------------------------------------------------------------
__global__ __launch_bounds__(256) void k_out(
    const unsigned short* __restrict__ Ag,
    const float* __restrict__ Wo, const float* __restrict__ bo,
    float* __restrict__ out)
{
  __shared__ __align__(16) unsigned short wt[128 * 128];
  const int tid = threadIdx.x, lane = tid & 63, wid = tid >> 6;
  const int l15 = lane & 15, g = lane >> 4;
  const int r0 = blockIdx.x * 64 + wid * 16;

  for (int i = 0; i < 64; ++i) {
    int idx = i * 256 + tid;
    int k = idx >> 7, n = idx & 127;
    int cs = (k >> 3) ^ (n & 7);
    wt[n * 128 + cs * 8 + (k & 7)] = f2bf(Wo[idx]);
  }

  short8 af[4];
  const unsigned short* ap = Ag + (r0 + l15) * 128 + g * 8;
#pragma unroll
  for (int kt = 0; kt < 4; ++kt) af[kt] = *(const short8*)(ap + kt * 32);

  float bias[8];
#pragma unroll
  for (int nt = 0; nt < 8; ++nt) bias[nt] = bo[nt * 16 + l15];

  __syncthreads();

  f32x4 acc[8];
#pragma unroll
  for (int nt = 0; nt < 8; ++nt) acc[nt] = (f32x4){0.f, 0.f, 0.f, 0.f};
#pragma unroll
  for (int nt = 0; nt < 8; ++nt) {
    int n = nt * 16 + l15;
#pragma unroll
    for (int ks = 0; ks < 4; ++ks) {
      int cs = (ks * 4 + g) ^ (n & 7);
      short8 bf = *(const short8*)&wt[n * 128 + cs * 8];
      acc[nt] = MFMA16(af[ks], bf, acc[nt]);
    }
  }
#pragma unroll
  for (int nt = 0; nt < 8; ++nt) {
    int col = nt * 16 + l15;
#pragma unroll
    for (int r = 0; r < 4; ++r)
      out[(r0 + g * 4 + r) * 128 + col] = acc[nt][r] + bias[nt];
  }
}

// ---------------------------------------------------------------------------
extern "C" void kernel_launch(void* const* d_in, const int* in_sizes, int n_in,
                              void* d_out, int out_size, void* d_ws, size_t ws_size,
                              hipStream_t stream) {
  const float* x  = (const float*)d_in[0];
  const float* Wq = (const float*)d_in[1];
  const float* bq = (const float*)d_in[2];
  const float* Wk = (const float*)d_in[3];
  const float* bk = (const float*)d_in[4];
  const float* Wv = (const float*)d_in[5];
  const float* bv = (const float*)d_in[6];
  const float* Wo = (const float*)d_in[7];
  const float* bo = (const float*)d_in[8];

  const int NTOK = 4 * 4096;               // B*S
  unsigned short* Qg  = (unsigned short*)d_ws;
  unsigned short* Kg  = Qg  + NTOK * 128;
  unsigned short* Vtg = Kg  + NTOK * 128;
  unsigned short* Ag  = Vtg + NTOK * 128;  // total 16 MB of d_ws

  k_proj<<<256, 256, 0, stream>>>(x, Wq, bq, Wk, bk, Wv, bv, Qg, Kg, Vtg);
  k_attn<<<512, 256, 0, stream>>>(Qg, Kg, Vtg, Ag);
  k_out<<<256, 256, 0, stream>>>(Ag, Wo, bo, (float*)d_out);
}